// Round 8
// baseline (893.837 us; speedup 1.0000x reference)
//
#include <hip/hip_runtime.h>

typedef unsigned short u16;
typedef unsigned int   u32;
typedef unsigned long long u64;
typedef short s8v __attribute__((ext_vector_type(8)));   // 8 bf16 (4 VGPRs)
typedef float f4v __attribute__((ext_vector_type(4)));   // 4 fp32 acc
typedef float f2v __attribute__((ext_vector_type(2)));   // packed fp32 pair
typedef unsigned long long ull2 __attribute__((ext_vector_type(2)));

#define STRIDE 168           // LDS A-row stride in elems (336B, 16B-aligned rows)
#define CAP 256              // ball-query cap (Poisson lambda~137, P(>256)~1e-24)
#define OFF_G1 0             // swizzled-weight elem offsets in ws (128 KiB total)
#define OFF_G2 12288
#define OFF_G3 28672
#define OFF_G4 49152
#define NBLK 240             // cooperative grid
#define PAIR_TASKS 2048      // 2 batches x 1024 samples per XCD-pair

// flags in module memory; one 64B line per counter. Re-zeroed by swz_kernel.
__device__ u32 g_prog[16*16];     // per-batch fps progress
__device__ u32 g_ticket[8*16];    // per-pair task tickets (pair p = batches 2p,2p+1)

__device__ __forceinline__ u16 f2bf(float f){
  u32 u = __float_as_uint(f);
  return (u16)((u + 0x7FFFu + ((u>>16)&1u)) >> 16);      // RNE
}
// exact fp32, no-FMA, numpy order: (dx*dx + dy*dy) + dz*dz
__device__ __forceinline__ float sqd(float ax,float ay,float az,float bx,float by,float bz){
  float dx=ax-bx, dy=ay-by, dz=az-bz;
  return __fadd_rn(__fadd_rn(__fmul_rn(dx,dx),__fmul_rn(dy,dy)),__fmul_rn(dz,dz));
}

// DPP u32 max step (dist bits are positive floats -> unsigned == float ordering)
#define WMAX_STEP(v, CTRL) { \
  u32 _t = (u32)__builtin_amdgcn_update_dpp(0, (int)(v), CTRL, 0xf, 0xf, false); \
  (v) = (v) > _t ? (v) : _t; }
// u64 max step via DPP (all lanes valid with row_ror patterns)
#define QMAX64(k, CTRL) { \
  u32 _lo=(u32)(k), _hi=(u32)((k)>>32); \
  u32 _plo=(u32)__builtin_amdgcn_update_dpp(0,(int)_lo,CTRL,0xf,0xf,true); \
  u32 _phi=(u32)__builtin_amdgcn_update_dpp(0,(int)_hi,CTRL,0xf,0xf,true); \
  u64 _o=((u64)_phi<<32)|_plo; (k) = (k)>_o ? (k) : _o; }

// relaxed agent-scope store/load (coherence-point path; proven cross-XCD
// coherent by R3-R7 passing runs)
__device__ __forceinline__ void st_rlx(u32* p, u32 v){
  __hip_atomic_store(p, v, __ATOMIC_RELAXED, __HIP_MEMORY_SCOPE_AGENT);
}
__device__ __forceinline__ u32 ld_rlx(const u32* p){
  return __hip_atomic_load(p, __ATOMIC_RELAXED, __HIP_MEMORY_SCOPE_AGENT);
}

// ---------------------------------------------------------------- weight swizzle (f32 -> bf16 frags)
__global__ __launch_bounds__(256) void swz_kernel(const float* __restrict__ W1,const float* __restrict__ W2,
                                                  const float* __restrict__ W3,const float* __restrict__ W4,
                                                  u16* __restrict__ wsw){
  int T = blockIdx.x*256 + threadIdx.x;       // 8192 threads
  const float* W; int rel, base, kind;
  if(T < 1536){ rel=T;      base=OFF_G1; W=W1; kind=0; }
  else if(T < 3584){ rel=T-1536; base=OFF_G2; W=W2; kind=1; }
  else if(T < 6144){ rel=T-3584; base=OFF_G3; W=W3; kind=0; }
  else         { rel=T-6144; base=OFF_G4; W=W4; kind=1; }
  int chunk=rel>>6, lane=rel&63, c=chunk>>3, t=chunk&7, quad=lane>>4, l15=lane&15;
  u16 v[8];
  #pragma unroll
  for(int j=0;j<8;j++){
    int kp = c*32 + quad*8 + j, n = t*16 + l15;
    int src = (kind==0) ? (kp<3 ? kp : (kp>=32 ? kp-29 : -1)) : kp;
    v[j] = (src<0) ? (u16)0 : f2bf(W[src*128 + n]);
  }
  int4 o;
  o.x=(int)((u32)v[0]|((u32)v[1]<<16)); o.y=(int)((u32)v[2]|((u32)v[3]<<16));
  o.z=(int)((u32)v[4]|((u32)v[5]<<16)); o.w=(int)((u32)v[6]|((u32)v[7]<<16));
  *(int4*)&wsw[base + rel*8] = o;
  if(T==0){
    #pragma unroll
    for(int i=0;i<256;i++) g_prog[i]=0;
    #pragma unroll
    for(int i=0;i<128;i++) g_ticket[i]=0;
  }
}

// ---------------------------------------------------------------- MLP helpers
__device__ __forceinline__ void zero_C(f4v C[2][8]){
  #pragma unroll
  for(int mt=0;mt<2;mt++)
    #pragma unroll
    for(int t=0;t<8;t++) C[mt][t] = (f4v){0.f,0.f,0.f,0.f};
}
__device__ __forceinline__ void load_bias(const float* bsrc,int l15,float bb[8]){
  #pragma unroll
  for(int t=0;t<8;t++) bb[t]=bsrc[t*16+l15];
}
template<int KC>
__device__ __forceinline__ void run_gemm(const u16* A, const u16* BW,
                                         int lane,int l15,int quad, f4v C[2][8]){
  s8v af[2][KC];
  #pragma unroll
  for(int mt=0;mt<2;mt++)
    #pragma unroll
    for(int c=0;c<KC;c++)
      af[mt][c] = *(const s8v*)&A[(mt*16+l15)*STRIDE + c*32 + quad*8];
  #pragma unroll
  for(int t=0;t<8;t++){
    #pragma unroll
    for(int c=0;c<KC;c++){
      s8v bw = *(const s8v*)&BW[((c*8+t)*64 + lane)*8];
      C[0][t] = __builtin_amdgcn_mfma_f32_16x16x32_bf16(af[0][c],bw,C[0][t],0,0,0);
      C[1][t] = __builtin_amdgcn_mfma_f32_16x16x32_bf16(af[1][c],bw,C[1][t],0,0,0);
    }
  }
}
__device__ __forceinline__ void store_act(u16* A,int l15,int quad,f4v C[2][8],const float bb[8]){
  #pragma unroll
  for(int mt=0;mt<2;mt++)
    #pragma unroll
    for(int t=0;t<8;t++)
      #pragma unroll
      for(int r=0;r<4;r++){
        float v = fmaxf(C[mt][t][r]+bb[t], 0.f);
        A[(mt*16+quad*4+r)*STRIDE + t*16 + l15] = f2bf(v);
      }
}
__device__ __forceinline__ void write_xyz_chunk0(u16* A,int lane,float xn,float yn,float zn){
  if(lane<32){
    u16* row=&A[lane*STRIDE];
    row[0]=f2bf(xn); row[1]=f2bf(yn); row[2]=f2bf(zn); row[3]=0;
    #pragma unroll
    for(int q=0;q<7;q++) *(u64*)&row[4+q*4] = 0ull;   // cols 4..31 zero
  }
}

// ---------------------------------------------------------------- fused producer/consumer kernel
// R8: centers accumulate in LDS R[] (the proven 608us structure — NO global
//   stores in wave 0's serial loop). Wave 1 publishes in chunks: at
//   (i&31)==0 it copies window [i-32,i-1] R->global via 32 parallel sc1
//   stores (fire-and-forget); at (i&31)==4 (5700cy later, stores retired)
//   it waits vmcnt(0) (free) and sets prog=i-4. Final window [992,1023]
//   is copied between two block barriers after the loop (no race with the
//   consumer LDS view reuse). R3/R7 evidence: wall == producer-only time,
//   so the per-iter sc1 stores are the prime suspect for 608->738.
// consumers: XCD batch-affinity (R6) + work stealing; relaxed polls.
union SMem {
  struct { float S[4096*3]; float R[1024*3]; u64 red[2][8]; } f;       // fps view (~60.5 KB)
  struct { u64 Bc[8][CAP+2]; int sel[8][32]; u16 A[8][32*STRIDE]; } c; // consumer (~101.1 KB)
};

__global__ __launch_bounds__(512,2) void fused_kernel(const float* __restrict__ xyz,
    const float* __restrict__ feats, const u16* __restrict__ wsw,
    const float* __restrict__ b1,const float* __restrict__ b2,
    const float* __restrict__ b3,const float* __restrict__ b4,
    float* __restrict__ newxyz, float* __restrict__ fout){
  __shared__ __align__(16) SMem U;
  const int tid=threadIdx.x, lane=tid&63, wv=tid>>6;

  if(blockIdx.x < 16){
    // ---------------- FPS (baseline body; LDS R[] accumulation) ----------------
    const int b = blockIdx.x;
    float* S = U.f.S;
    float* R = U.f.R;
    u32* nbu = (u32*)(newxyz + (size_t)b*3072);
    const float* xb = xyz + (size_t)b*4096*3;
    #pragma unroll
    for(int j=0;j<6;j++) ((float4*)S)[j*512+tid] = ((const float4*)xb)[j*512+tid];
    __syncthreads();
    f2v X[4],Y[4],Z[4],DM[4];
    const float x0=S[0], y0=S[1], z0=S[2];
    {
      #pragma clang fp contract(off)
      const f2v fx2={x0,x0}, fy2={y0,y0}, fz2={z0,z0};
      #pragma unroll
      for(int k2=0;k2<4;k2++){
        int p0 = tid*8 + 2*k2;
        X[k2] = (f2v){S[p0*3],   S[p0*3+3]};
        Y[k2] = (f2v){S[p0*3+1], S[p0*3+4]};
        Z[k2] = (f2v){S[p0*3+2], S[p0*3+5]};
        f2v dx=X[k2]-fx2, dy=Y[k2]-fy2, dz=Z[k2]-fz2;
        DM[k2] = (dx*dx + dy*dy) + dz*dz;
      }
    }
    if(tid==0){ R[0]=x0; R[1]=y0; R[2]=z0; }
    for(int i=1;i<1024;i++){
      f2v a = __builtin_elementwise_max(DM[0],DM[1]);
      f2v cc = __builtin_elementwise_max(DM[2],DM[3]);
      f2v mm = __builtin_elementwise_max(a,cc);
      float vm = fmaxf(mm[0], mm[1]);
      u32 m8 = 0;
      #pragma unroll
      for(int j=0;j<8;j++) m8 |= (DM[j>>1][j&1]==vm) ? (1u<<j) : 0u;
      int jm = __ffs(m8)-1;
      u32 w = __float_as_uint(vm);
      WMAX_STEP(w, 0x111); WMAX_STEP(w, 0x112); WMAX_STEP(w, 0x114);
      WMAX_STEP(w, 0x118); WMAX_STEP(w, 0x142); WMAX_STEP(w, 0x143);
      u32 wm = (u32)__builtin_amdgcn_readlane((int)w, 63);
      u64 msk = __ballot(__float_as_uint(vm) == wm);
      int ldr = __ffsll((unsigned long long)msk) - 1;
      int pj  = __builtin_amdgcn_readlane(jm, ldr);
      int p   = (wv*64 + ldr)*8 + pj;
      if(lane==0) U.f.red[i&1][wv] = ((u64)wm<<32) | (u32)(~(u32)p);
      // fence-free barrier: wait LDS only
      __asm__ __volatile__("s_waitcnt lgkmcnt(0)" ::: "memory");
      __builtin_amdgcn_s_barrier();
      __builtin_amdgcn_sched_barrier(0);
      u64 k = U.f.red[i&1][lane&7];
      QMAX64(k, 0x121); QMAX64(k, 0x122); QMAX64(k, 0x124);   // row_ror 1,2,4
      int far = (int)(~(u32)k) & 4095;
      float fx=S[far*3], fy=S[far*3+1], fz=S[far*3+2];
      if(tid==0){ R[i*3]=fx; R[i*3+1]=fy; R[i*3+2]=fz; }      // LDS only
      // ---- chunked publisher on wave 1 (off wave 0's critical path) ----
      if(wv==1){
        if((i&31)==0){                    // i>=32 guaranteed (i&31==0, i>=1 -> i>=32)
          if(lane<32){
            int s0 = i-32+lane;           // window [i-32, i-1]: R complete
            float a0=R[s0*3], a1=R[s0*3+1], a2=R[s0*3+2];
            u32* r = nbu + (size_t)s0*3;
            st_rlx(&r[0], __float_as_uint(a0));   // fire-and-forget sc1
            st_rlx(&r[1], __float_as_uint(a1));
            st_rlx(&r[2], __float_as_uint(a2));
          }
        } else if((i&31)==4 && i>=36){    // window issued 4 iters (~5.7Kcy) ago
          // wave-1's own stores retired -> vmcnt(0) is free
          __asm__ __volatile__("s_waitcnt vmcnt(0)" ::: "memory");
          if(lane==0) st_rlx(&g_prog[b*16], (u32)(i-4));  // samples < i-4 ready
        }
      }
      {
        #pragma clang fp contract(off)
        const f2v fx2={fx,fx}, fy2={fy,fy}, fz2={fz,fz};
        #pragma unroll
        for(int k2c=0;k2c<4;k2c++){
          f2v dx=X[k2c]-fx2, dy=Y[k2c]-fy2, dz=Z[k2c]-fz2;
          f2v s2 = (dx*dx + dy*dy) + dz*dz;
          DM[k2c] = __builtin_elementwise_min(DM[k2c], s2);
        }
      }
    }
    // final window [992,1023]: copy between two barriers (R[1023] visible;
    // reads complete before consumer LDS view reuse), then publish 1024.
    __syncthreads();
    if(wv==1 && lane<32){
      int s0 = 992+lane;
      float a0=R[s0*3], a1=R[s0*3+1], a2=R[s0*3+2];
      u32* r = nbu + (size_t)s0*3;
      st_rlx(&r[0], __float_as_uint(a0));
      st_rlx(&r[1], __float_as_uint(a1));
      st_rlx(&r[2], __float_as_uint(a2));
    }
    __syncthreads();
    if(wv==1){
      __asm__ __volatile__("s_waitcnt vmcnt(0)" ::: "memory");
      if(lane==0) st_rlx(&g_prog[b*16], 1024u);
    }
  }
  __syncthreads();   // block-local; fps blocks: LDS view transition (S/R dead -> Bc/A)

  // ---------------- persistent consumer (fused ballq + mlp, per-wave) ----------------
  const int quad=lane>>4, l15=lane&15;
  u64* Bc   = U.c.Bc[wv];
  int* selw = U.c.sel[wv];
  u16* A    = U.c.A[wv];
  const u64 lt = (1ull<<lane)-1ull;
  // physical XCD id -> batch-pair affinity (HW-measured: returns 0..7)
  u32 xcc;
  __asm__ __volatile__("s_getreg_b32 %0, hwreg(HW_REG_XCC_ID)" : "=s"(xcc));
  const int mypair = (int)(xcc & 7u);
  for(int pk=0; pk<8; pk++){                 // own pair first, then steal
    const int pair = (mypair + pk) & 7;
    for(;;){
      int t;
      if(lane==0) t = (int)atomicAdd(&g_ticket[pair*16], 1u);
      t = __shfl(t, 0);
      if(t >= PAIR_TASKS) break;
      const int s = t>>1, tb = pair*2 + (t&1), widx = (tb<<10) + s;
      // relaxed poll: cache-bypassing load, no invalidate
      for(;;){
        u32 pr = ld_rlx(&g_prog[tb*16]);
        if(pr > (u32)s) break;
        __builtin_amdgcn_s_sleep(16);
      }
      __asm__ __volatile__("" ::: "memory");   // keep loads below the poll
      const float* xb = xyz + (size_t)tb*4096*3;
      // centers via relaxed agent loads (same coherence path as producer stores)
      const u32* cpu = (const u32*)(newxyz + (size_t)widx*3);
      const float cx = __uint_as_float(ld_rlx(&cpu[0]));
      const float cy = __uint_as_float(ld_rlx(&cpu[1]));
      const float cz = __uint_as_float(ld_rlx(&cpu[2]));

      // ---- ball query (1 wave) ----
      int base=0;
      for(int kk=0;kk<64;kk++){
        int p = kk*64 + lane;
        float d = sqd(cx,cy,cz, xb[p*3],xb[p*3+1],xb[p*3+2]);
        bool in = (d <= 0.04f);
        u64 m = __ballot(in);
        if(in){ int pos = base + __popcll(m&lt); if(pos<CAP) Bc[pos] = ((u64)__float_as_uint(d)<<32)|(u32)p; }
        base += __popcll(m);
      }
      int cnt = base>CAP ? CAP : base;
      if(cnt > 32){
        if(lane==0){ Bc[cnt]=~0ull; Bc[cnt+1]=~0ull; }     // sentinels (> any key)
        int cnt2 = (cnt+1)&~1;
        for(int c=lane; c<cnt; c+=64){
          u64 key = Bc[c]; int r=0;
          for(int t2=0;t2<cnt2;t2+=2){
            ull2 k2 = *(const ull2*)&Bc[t2];               // b128: 2 keys/read
            r += (k2[0] < key) ? 1 : 0;
            r += (k2[1] < key) ? 1 : 0;
          }
          if(r < 32) selw[r] = (int)(u32)key;              // low 32 = point index
        }
      } else {
        for(int c=lane; c<cnt; c+=64) selw[c] = (int)(u32)Bc[c];
        int need = 32 - cnt, bq = 0;
        for(int kk=0; kk<64 && bq<need; kk++){
          int p = kk*64 + lane;
          float d = sqd(cx,cy,cz, xb[p*3],xb[p*3+1],xb[p*3+2]);
          bool o = !(d <= 0.04f);
          u64 m = __ballot(o);
          if(o){ int pos = bq + __popcll(m&lt); if(pos<need) selw[cnt+pos] = p; }
          bq += __popcll(m);
        }
      }

      // ---- MLP (1 wave, barrier-free: same-wave LDS ordered by lgkmcnt) ----
      const int gi_f = selw[lane>>1] & 4095;
      const int gi_x = selw[lane & 31] & 4095;
      {
        int r2=lane>>1, h=lane&1;
        const float* fs = feats + ((size_t)tb*4096 + gi_f)*64 + h*32;
        u16* fd = &A[r2*STRIDE + 32 + h*32];
        #pragma unroll
        for(int j=0;j<8;j++){
          float4 v4 = ((const float4*)fs)[j];
          u64 pk4 = (u64)f2bf(v4.x) | ((u64)f2bf(v4.y)<<16)
                  | ((u64)f2bf(v4.z)<<32) | ((u64)f2bf(v4.w)<<48);
          *(u64*)&fd[j*4] = pk4;
        }
      }
      float xn=0.f,yn=0.f,zn=0.f;
      if(lane<32){
        const float* xp = xb + (size_t)gi_x*3;
        xn = xp[0]-cx; yn = xp[1]-cy; zn = xp[2]-cz;
      }
      write_xyz_chunk0(A,lane,xn,yn,zn);

      f4v C[2][8]; float bb[8];
      // GEMM1: f_in(32x96) @ W1 -> relu -> H1
      zero_C(C); load_bias(b1,l15,bb);
      run_gemm<3>(A, wsw+OFF_G1, lane,l15,quad, C);
      store_act(A,l15,quad,C,bb);
      // GEMM2: H1 @ W2 -> relu -> f_prime
      zero_C(C); load_bias(b2,l15,bb);
      run_gemm<4>(A, wsw+OFF_G2, lane,l15,quad, C);
      float fp[2][8][4]; float mean[8];
      #pragma unroll
      for(int t2=0;t2<8;t2++){
        float sm=0.f;
        #pragma unroll
        for(int mt=0;mt<2;mt++)
          #pragma unroll
          for(int r=0;r<4;r++){
            float v = fmaxf(C[mt][t2][r]+bb[t2], 0.f);
            fp[mt][t2][r]=v; sm+=v;
          }
        sm += __shfl_xor(sm,16); sm += __shfl_xor(sm,32);
        mean[t2] = sm*0.03125f;
      }
      #pragma unroll
      for(int mt=0;mt<2;mt++)
        #pragma unroll
        for(int t2=0;t2<8;t2++)
          #pragma unroll
          for(int r=0;r<4;r++)
            A[(mt*16+quad*4+r)*STRIDE + 32 + t2*16 + l15] = f2bf(fp[mt][t2][r]-mean[t2]);
      write_xyz_chunk0(A,lane,xn,yn,zn);   // w_in chunk0
      // GEMM3: w_in(32x160) @ W3 -> relu -> H3
      zero_C(C); load_bias(b3,l15,bb);
      run_gemm<5>(A, wsw+OFF_G3, lane,l15,quad, C);
      store_act(A,l15,quad,C,bb);
      // GEMM4: H3 @ W4 -> sigmoid -> alpha; f_out = sum_k alpha*f_prime
      zero_C(C); load_bias(b4,l15,bb);
      run_gemm<4>(A, wsw+OFF_G4, lane,l15,quad, C);
      float* fo = fout + (size_t)widx*128;
      #pragma unroll
      for(int t2=0;t2<8;t2++){
        float part=0.f;
        #pragma unroll
        for(int mt=0;mt<2;mt++)
          #pragma unroll
          for(int r=0;r<4;r++){
            float pre = C[mt][t2][r]+bb[t2];
            float aa = 1.f/(1.f+__expf(-pre));
            part += aa*fp[mt][t2][r];
          }
        part += __shfl_xor(part,16); part += __shfl_xor(part,32);
        if(quad==0) fo[t2*16+l15] = part;
      }
    }
  }
}

// ---------------------------------------------------------------- launch
extern "C" void kernel_launch(void* const* d_in, const int* in_sizes, int n_in,
                              void* d_out, int out_size, void* d_ws, size_t ws_size,
                              hipStream_t stream){
  (void)in_sizes; (void)n_in; (void)out_size; (void)ws_size;
  const float* xyz   = (const float*)d_in[0];
  const float* feats = (const float*)d_in[1];
  const float* W1 = (const float*)d_in[2]; const float* b1 = (const float*)d_in[3];
  const float* W2 = (const float*)d_in[4]; const float* b2 = (const float*)d_in[5];
  const float* W3 = (const float*)d_in[6]; const float* b3 = (const float*)d_in[7];
  const float* W4 = (const float*)d_in[8]; const float* b4 = (const float*)d_in[9];
  float* out = (float*)d_out;
  float* newxyz = out;               // (16,1024,3) f32
  float* fout   = out + 16*1024*3;   // (16,1024,128) f32
  u16* wsw = (u16*)d_ws;             // 128 KiB swizzled bf16 weights — only ws use

  hipLaunchKernelGGL(swz_kernel, dim3(32), dim3(256), 0, stream, W1,W2,W3,W4, wsw);
  void* args[9];
  args[0]=(void*)&xyz;  args[1]=(void*)&feats; args[2]=(void*)&wsw;
  args[3]=(void*)&b1;   args[4]=(void*)&b2;    args[5]=(void*)&b3; args[6]=(void*)&b4;
  args[7]=(void*)&newxyz; args[8]=(void*)&fout;
  hipLaunchCooperativeKernel((void*)fused_kernel, dim3(NBLK), dim3(512), args, 0, stream);
}

// Round 9
// 829.581 us; speedup vs baseline: 1.0775x; 1.0775x over previous
//
#include <hip/hip_runtime.h>

typedef unsigned short u16;
typedef unsigned int   u32;
typedef unsigned long long u64;
typedef short s8v __attribute__((ext_vector_type(8)));   // 8 bf16 (4 VGPRs)
typedef float f4v __attribute__((ext_vector_type(4)));   // 4 fp32 acc
typedef float f2v __attribute__((ext_vector_type(2)));   // packed fp32 pair
typedef unsigned long long ull2 __attribute__((ext_vector_type(2)));

#define STRIDE 168           // LDS A-row stride in elems (336B, 16B-aligned rows)
#define CAP 256              // ball-query cap (Poisson lambda~137, P(>256)~1e-24)
#define OFF_G1 0             // swizzled-weight elem offsets in ws (128 KiB total)
#define OFF_G2 12288
#define OFF_G3 28672
#define OFF_G4 49152
#define NBLK 240             // cooperative grid
#define PAIR_TASKS 2048      // 2 batches x 1024 samples per XCD-pair
#define WREG 12944           // consumer bytes/wave: Bc 2064 + sel 128 + A 10752
#define HDR 160              // LDS header: fps_done + red2[2][4] (never aliased)

// flags in module memory; one 64B line per counter. Re-zeroed by swz_kernel.
__device__ u32 g_prog[16*16];     // per-batch fps progress
__device__ u32 g_ticket[8*16];    // per-pair task tickets (pair p = batches 2p,2p+1)

__device__ __forceinline__ u16 f2bf(float f){
  u32 u = __float_as_uint(f);
  return (u16)((u + 0x7FFFu + ((u>>16)&1u)) >> 16);      // RNE
}
// exact fp32, no-FMA, numpy order: (dx*dx + dy*dy) + dz*dz
__device__ __forceinline__ float sqd(float ax,float ay,float az,float bx,float by,float bz){
  float dx=ax-bx, dy=ay-by, dz=az-bz;
  return __fadd_rn(__fadd_rn(__fmul_rn(dx,dx),__fmul_rn(dy,dy)),__fmul_rn(dz,dz));
}

// DPP u32 max step (dist bits are positive floats -> unsigned == float ordering)
#define WMAX_STEP(v, CTRL) { \
  u32 _t = (u32)__builtin_amdgcn_update_dpp(0, (int)(v), CTRL, 0xf, 0xf, false); \
  (v) = (v) > _t ? (v) : _t; }
// u64 max step via DPP (all lanes valid with quad_perm patterns)
#define QMAX64(k, CTRL) { \
  u32 _lo=(u32)(k), _hi=(u32)((k)>>32); \
  u32 _plo=(u32)__builtin_amdgcn_update_dpp(0,(int)_lo,CTRL,0xf,0xf,true); \
  u32 _phi=(u32)__builtin_amdgcn_update_dpp(0,(int)_hi,CTRL,0xf,0xf,true); \
  u64 _o=((u64)_phi<<32)|_plo; (k) = (k)>_o ? (k) : _o; }

// relaxed agent-scope store/load (coherence-point path; proven cross-XCD
// coherent by R3-R8 passing runs)
__device__ __forceinline__ void st_rlx(u32* p, u32 v){
  __hip_atomic_store(p, v, __ATOMIC_RELAXED, __HIP_MEMORY_SCOPE_AGENT);
}
__device__ __forceinline__ u32 ld_rlx(const u32* p){
  return __hip_atomic_load(p, __ATOMIC_RELAXED, __HIP_MEMORY_SCOPE_AGENT);
}
// LDS relaxed ops (plain ds_read/ds_write; atomics prevent compiler reg-caching)
__device__ __forceinline__ void st_lds64(u64* p, u64 v){
  __hip_atomic_store(p, v, __ATOMIC_RELAXED, __HIP_MEMORY_SCOPE_WORKGROUP);
}
__device__ __forceinline__ u64 ld_lds64(const u64* p){
  return __hip_atomic_load(p, __ATOMIC_RELAXED, __HIP_MEMORY_SCOPE_WORKGROUP);
}

// ---------------------------------------------------------------- weight swizzle (f32 -> bf16 frags)
__global__ __launch_bounds__(256) void swz_kernel(const float* __restrict__ W1,const float* __restrict__ W2,
                                                  const float* __restrict__ W3,const float* __restrict__ W4,
                                                  u16* __restrict__ wsw){
  int T = blockIdx.x*256 + threadIdx.x;       // 8192 threads
  const float* W; int rel, base, kind;
  if(T < 1536){ rel=T;      base=OFF_G1; W=W1; kind=0; }
  else if(T < 3584){ rel=T-1536; base=OFF_G2; W=W2; kind=1; }
  else if(T < 6144){ rel=T-3584; base=OFF_G3; W=W3; kind=0; }
  else         { rel=T-6144; base=OFF_G4; W=W4; kind=1; }
  int chunk=rel>>6, lane=rel&63, c=chunk>>3, t=chunk&7, quad=lane>>4, l15=lane&15;
  u16 v[8];
  #pragma unroll
  for(int j=0;j<8;j++){
    int kp = c*32 + quad*8 + j, n = t*16 + l15;
    int src = (kind==0) ? (kp<3 ? kp : (kp>=32 ? kp-29 : -1)) : kp;
    v[j] = (src<0) ? (u16)0 : f2bf(W[src*128 + n]);
  }
  int4 o;
  o.x=(int)((u32)v[0]|((u32)v[1]<<16)); o.y=(int)((u32)v[2]|((u32)v[3]<<16));
  o.z=(int)((u32)v[4]|((u32)v[5]<<16)); o.w=(int)((u32)v[6]|((u32)v[7]<<16));
  *(int4*)&wsw[base + rel*8] = o;
  if(T==0){
    #pragma unroll
    for(int i=0;i<256;i++) g_prog[i]=0;
    #pragma unroll
    for(int i=0;i<128;i++) g_ticket[i]=0;
  }
}

// ---------------------------------------------------------------- MLP helpers
__device__ __forceinline__ void zero_C(f4v C[2][8]){
  #pragma unroll
  for(int mt=0;mt<2;mt++)
    #pragma unroll
    for(int t=0;t<8;t++) C[mt][t] = (f4v){0.f,0.f,0.f,0.f};
}
__device__ __forceinline__ void load_bias(const float* bsrc,int l15,float bb[8]){
  #pragma unroll
  for(int t=0;t<8;t++) bb[t]=bsrc[t*16+l15];
}
template<int KC>
__device__ __forceinline__ void run_gemm(const u16* A, const u16* BW,
                                         int lane,int l15,int quad, f4v C[2][8]){
  s8v af[2][KC];
  #pragma unroll
  for(int mt=0;mt<2;mt++)
    #pragma unroll
    for(int c=0;c<KC;c++)
      af[mt][c] = *(const s8v*)&A[(mt*16+l15)*STRIDE + c*32 + quad*8];
  #pragma unroll
  for(int t=0;t<8;t++){
    #pragma unroll
    for(int c=0;c<KC;c++){
      s8v bw = *(const s8v*)&BW[((c*8+t)*64 + lane)*8];
      C[0][t] = __builtin_amdgcn_mfma_f32_16x16x32_bf16(af[0][c],bw,C[0][t],0,0,0);
      C[1][t] = __builtin_amdgcn_mfma_f32_16x16x32_bf16(af[1][c],bw,C[1][t],0,0,0);
    }
  }
}
__device__ __forceinline__ void store_act(u16* A,int l15,int quad,f4v C[2][8],const float bb[8]){
  #pragma unroll
  for(int mt=0;mt<2;mt++)
    #pragma unroll
    for(int t=0;t<8;t++)
      #pragma unroll
      for(int r=0;r<4;r++){
        float v = fmaxf(C[mt][t][r]+bb[t], 0.f);
        A[(mt*16+quad*4+r)*STRIDE + t*16 + l15] = f2bf(v);
      }
}
__device__ __forceinline__ void write_xyz_chunk0(u16* A,int lane,float xn,float yn,float zn){
  if(lane<32){
    u16* row=&A[lane*STRIDE];
    row[0]=f2bf(xn); row[1]=f2bf(yn); row[2]=f2bf(zn); row[3]=0;
    #pragma unroll
    for(int q=0;q<7;q++) *(u64*)&row[4+q*4] = 0ull;   // cols 4..31 zero
  }
}

// ---------------------------------------------------------------- fused producer/consumer kernel
// R9: 4-wave FPS (1 wave/SIMD). R1 PMC: per-producer-CU VALUBusy ~60% ->
//   8 waves = 2/SIMD serialize identical VALU chains on the issue port
//   (~600cy/SIMD/iter). 4 waves x 16pts/thread halves issue serialization.
//   In-loop sync = 4-wave LDS flag-sync (no s_barrier -> waves 4-7 free):
//   slot u64 = {dist[63:32], (~p)[31:20], seq=i&1023}; parity dbuf; spin
//   until all 4 slots carry this round's tag; reduce = 2 quad_perm QMAX64.
//   Waves 4-7 idle-spin on fps_done during FPS (no issue-slot theft), then
//   consume. Centers/publish = R6 exact (proven 738): per-iter st_rlx by
//   tid==0, vmcnt(3)+prog at (i&31)==31, final vmcnt(0)+1024.
// consumers: XCD batch-affinity (R6) + work stealing; relaxed polls. LDS:
//   [HDR 160B: fps_done,red2][wave regions 0-7, 12944B each]; S aliases
//   regions 0-3 (49152 <= 51776); red2 in header -> never clobbered.
__global__ __launch_bounds__(512,2) void fused_kernel(const float* __restrict__ xyz,
    const float* __restrict__ feats, const u16* __restrict__ wsw,
    const float* __restrict__ b1,const float* __restrict__ b2,
    const float* __restrict__ b3,const float* __restrict__ b4,
    float* __restrict__ newxyz, float* __restrict__ fout){
  __shared__ __align__(16) char LB[HDR + 8*WREG];   // 103712 B
  const int tid=threadIdx.x, lane=tid&63, wv=tid>>6;
  u32* fps_done = (u32*)LB;
  u64* red2 = (u64*)(LB + 16);                      // red2[parity*4 + wv], 64B

  if(blockIdx.x < 16){
    const int b = blockIdx.x;
    float* S = (float*)(LB + HDR);                  // 48KB, aliases regions 0-3
    const float* xb = xyz + (size_t)b*4096*3;
    #pragma unroll
    for(int j=0;j<6;j++) ((float4*)S)[j*512+tid] = ((const float4*)xb)[j*512+tid];
    if(tid==0){
      *fps_done = 0;
      #pragma unroll
      for(int q=0;q<8;q++) red2[q] = ~0ull;         // tag 1023: no false match for i=1..1022
    }
    __syncthreads();                                 // once, all 8 waves

    if(wv < 4){
      // ---------------- FPS: 4 waves, 16 pts/thread ----------------
      f2v X[8],Y[8],Z[8],DM[8];
      const float x0=S[0], y0=S[1], z0=S[2];
      {
        #pragma clang fp contract(off)
        const f2v fx2={x0,x0}, fy2={y0,y0}, fz2={z0,z0};
        #pragma unroll
        for(int k2=0;k2<8;k2++){
          int p0 = tid*16 + 2*k2;
          X[k2] = (f2v){S[p0*3],   S[p0*3+3]};
          Y[k2] = (f2v){S[p0*3+1], S[p0*3+4]};
          Z[k2] = (f2v){S[p0*3+2], S[p0*3+5]};
          f2v dx=X[k2]-fx2, dy=Y[k2]-fy2, dz=Z[k2]-fz2;
          DM[k2] = (dx*dx + dy*dy) + dz*dz;
        }
      }
      u32* nbu = (u32*)(newxyz + (size_t)b*3072);
      if(tid==0){
        st_rlx(&nbu[0], __float_as_uint(x0));
        st_rlx(&nbu[1], __float_as_uint(y0));
        st_rlx(&nbu[2], __float_as_uint(z0));
      }
      for(int i=1;i<1024;i++){
        // local max over 16 pts (8 f2v)
        f2v a0 = __builtin_elementwise_max(DM[0],DM[1]);
        f2v a1 = __builtin_elementwise_max(DM[2],DM[3]);
        f2v a2 = __builtin_elementwise_max(DM[4],DM[5]);
        f2v a3 = __builtin_elementwise_max(DM[6],DM[7]);
        f2v b0 = __builtin_elementwise_max(a0,a1);
        f2v b1v= __builtin_elementwise_max(a2,a3);
        f2v mm = __builtin_elementwise_max(b0,b1v);
        float vm = fmaxf(mm[0], mm[1]);
        // first-occurrence local index (bit j <-> pt j, 16 pts)
        u32 m16 = 0;
        #pragma unroll
        for(int j=0;j<16;j++) m16 |= (DM[j>>1][j&1]==vm) ? (1u<<j) : 0u;
        int jm = __ffs(m16)-1;
        // wave max via DPP (6 steps), result lane 63
        u32 w = __float_as_uint(vm);
        WMAX_STEP(w, 0x111); WMAX_STEP(w, 0x112); WMAX_STEP(w, 0x114);
        WMAX_STEP(w, 0x118); WMAX_STEP(w, 0x142); WMAX_STEP(w, 0x143);
        u32 wm = (u32)__builtin_amdgcn_readlane((int)w, 63);
        u64 msk = __ballot(__float_as_uint(vm) == wm);
        int ldr = __ffsll((unsigned long long)msk) - 1;
        int pj  = __builtin_amdgcn_readlane(jm, ldr);
        int p   = (wv*64 + ldr)*16 + pj;               // global idx, <=4095 (12 bits)
        // ---- 4-wave flag-sync reduce (no s_barrier) ----
        const u32 tag = (u32)i & 1023u;
        u64 mykey = ((u64)wm<<32) | ((u64)(((u32)~p)&0xFFFu)<<20) | tag;
        if(lane==0) st_lds64(&red2[(i&1)*4 + wv], mykey);
        __asm__ __volatile__("" ::: "memory");
        u64 k;
        do { k = ld_lds64(&red2[(i&1)*4 + (lane&3)]); }
        while(!__all((u32)(k & 1023ull) == tag));
        QMAX64(k, 0xB1);   // quad_perm [1,0,3,2]
        QMAX64(k, 0x4E);   // quad_perm [2,3,0,1]
        int far = (int)((~(u32)(k>>20)) & 0xFFFu);
        float fx=S[far*3], fy=S[far*3+1], fz=S[far*3+2];
        if(tid==0){
          u32* r = nbu + (size_t)i*3;
          st_rlx(&r[0], __float_as_uint(fx));
          st_rlx(&r[1], __float_as_uint(fy));
          st_rlx(&r[2], __float_as_uint(fz));
          if((i&31)==31){
            __asm__ __volatile__("s_waitcnt vmcnt(3)" ::: "memory");  // older stores retired
            st_rlx(&g_prog[b*16], (u32)i);                            // lag-one publish
          }
        }
        {
          #pragma clang fp contract(off)
          const f2v fx2={fx,fx}, fy2={fy,fy}, fz2={fz,fz};
          #pragma unroll
          for(int k2c=0;k2c<8;k2c++){
            f2v dx=X[k2c]-fx2, dy=Y[k2c]-fy2, dz=Z[k2c]-fz2;
            f2v s2 = (dx*dx + dy*dy) + dz*dz;
            DM[k2c] = __builtin_elementwise_min(DM[k2c], s2);
          }
        }
      }
      // exit sync (round 1024, tag 0, parity 0): all S reads complete before
      // any producer wave starts consuming (regions 0-3 alias S)
      {
        if(lane==0) st_lds64(&red2[0*4 + wv], 0ull);
        __asm__ __volatile__("" ::: "memory");
        u64 k;
        do { k = ld_lds64(&red2[0*4 + (lane&3)]); }
        while(!__all((u32)(k & 1023ull) == 0u));
      }
      if(tid==0){
        __asm__ __volatile__("s_waitcnt vmcnt(0)" ::: "memory");
        st_rlx(&g_prog[b*16], 1024u);
        __hip_atomic_store(fps_done, 1u, __ATOMIC_RELAXED, __HIP_MEMORY_SCOPE_WORKGROUP);
      }
    } else {
      // waves 4-7: idle during FPS (no issue-slot theft), then consume
      while(__hip_atomic_load(fps_done, __ATOMIC_RELAXED, __HIP_MEMORY_SCOPE_WORKGROUP) == 0u)
        __builtin_amdgcn_s_sleep(32);
    }
  }

  // ---------------- persistent consumer (fused ballq + mlp, per-wave) ----------------
  const int quad=lane>>4, l15=lane&15;
  char* wr  = LB + HDR + wv*WREG;
  u64* Bc   = (u64*)wr;
  int* selw = (int*)(wr + 2064);
  u16* A    = (u16*)(wr + 2192);
  const u64 lt = (1ull<<lane)-1ull;
  // physical XCD id -> batch-pair affinity (HW-measured: returns 0..7)
  u32 xcc;
  __asm__ __volatile__("s_getreg_b32 %0, hwreg(HW_REG_XCC_ID)" : "=s"(xcc));
  const int mypair = (int)(xcc & 7u);
  for(int pk=0; pk<8; pk++){                 // own pair first, then steal
    const int pair = (mypair + pk) & 7;
    for(;;){
      int t;
      if(lane==0) t = (int)atomicAdd(&g_ticket[pair*16], 1u);
      t = __shfl(t, 0);
      if(t >= PAIR_TASKS) break;
      const int s = t>>1, tb = pair*2 + (t&1), widx = (tb<<10) + s;
      // relaxed poll: cache-bypassing load, no invalidate
      for(;;){
        u32 pr = ld_rlx(&g_prog[tb*16]);
        if(pr > (u32)s) break;
        __builtin_amdgcn_s_sleep(16);
      }
      __asm__ __volatile__("" ::: "memory");   // keep loads below the poll
      const float* xb = xyz + (size_t)tb*4096*3;
      // centers via relaxed agent loads (same coherence path as producer stores)
      const u32* cpu = (const u32*)(newxyz + (size_t)widx*3);
      const float cx = __uint_as_float(ld_rlx(&cpu[0]));
      const float cy = __uint_as_float(ld_rlx(&cpu[1]));
      const float cz = __uint_as_float(ld_rlx(&cpu[2]));

      // ---- ball query (1 wave) ----
      int base=0;
      for(int kk=0;kk<64;kk++){
        int p = kk*64 + lane;
        float d = sqd(cx,cy,cz, xb[p*3],xb[p*3+1],xb[p*3+2]);
        bool in = (d <= 0.04f);
        u64 m = __ballot(in);
        if(in){ int pos = base + __popcll(m&lt); if(pos<CAP) Bc[pos] = ((u64)__float_as_uint(d)<<32)|(u32)p; }
        base += __popcll(m);
      }
      int cnt = base>CAP ? CAP : base;
      if(cnt > 32){
        if(lane==0){ Bc[cnt]=~0ull; Bc[cnt+1]=~0ull; }     // sentinels (> any key)
        int cnt2 = (cnt+1)&~1;
        for(int c=lane; c<cnt; c+=64){
          u64 key = Bc[c]; int r=0;
          for(int t2=0;t2<cnt2;t2+=2){
            ull2 k2 = *(const ull2*)&Bc[t2];               // b128: 2 keys/read
            r += (k2[0] < key) ? 1 : 0;
            r += (k2[1] < key) ? 1 : 0;
          }
          if(r < 32) selw[r] = (int)(u32)key;              // low 32 = point index
        }
      } else {
        for(int c=lane; c<cnt; c+=64) selw[c] = (int)(u32)Bc[c];
        int need = 32 - cnt, bq = 0;
        for(int kk=0; kk<64 && bq<need; kk++){
          int p = kk*64 + lane;
          float d = sqd(cx,cy,cz, xb[p*3],xb[p*3+1],xb[p*3+2]);
          bool o = !(d <= 0.04f);
          u64 m = __ballot(o);
          if(o){ int pos = bq + __popcll(m&lt); if(pos<need) selw[cnt+pos] = p; }
          bq += __popcll(m);
        }
      }

      // ---- MLP (1 wave, barrier-free: same-wave LDS ordered by lgkmcnt) ----
      const int gi_f = selw[lane>>1] & 4095;
      const int gi_x = selw[lane & 31] & 4095;
      {
        int r2=lane>>1, h=lane&1;
        const float* fs = feats + ((size_t)tb*4096 + gi_f)*64 + h*32;
        u16* fd = &A[r2*STRIDE + 32 + h*32];
        #pragma unroll
        for(int j=0;j<8;j++){
          float4 v4 = ((const float4*)fs)[j];
          u64 pk4 = (u64)f2bf(v4.x) | ((u64)f2bf(v4.y)<<16)
                  | ((u64)f2bf(v4.z)<<32) | ((u64)f2bf(v4.w)<<48);
          *(u64*)&fd[j*4] = pk4;
        }
      }
      float xn=0.f,yn=0.f,zn=0.f;
      if(lane<32){
        const float* xp = xb + (size_t)gi_x*3;
        xn = xp[0]-cx; yn = xp[1]-cy; zn = xp[2]-cz;
      }
      write_xyz_chunk0(A,lane,xn,yn,zn);

      f4v C[2][8]; float bb[8];
      // GEMM1: f_in(32x96) @ W1 -> relu -> H1
      zero_C(C); load_bias(b1,l15,bb);
      run_gemm<3>(A, wsw+OFF_G1, lane,l15,quad, C);
      store_act(A,l15,quad,C,bb);
      // GEMM2: H1 @ W2 -> relu -> f_prime
      zero_C(C); load_bias(b2,l15,bb);
      run_gemm<4>(A, wsw+OFF_G2, lane,l15,quad, C);
      float fp[2][8][4]; float mean[8];
      #pragma unroll
      for(int t2=0;t2<8;t2++){
        float sm=0.f;
        #pragma unroll
        for(int mt=0;mt<2;mt++)
          #pragma unroll
          for(int r=0;r<4;r++){
            float v = fmaxf(C[mt][t2][r]+bb[t2], 0.f);
            fp[mt][t2][r]=v; sm+=v;
          }
        sm += __shfl_xor(sm,16); sm += __shfl_xor(sm,32);
        mean[t2] = sm*0.03125f;
      }
      #pragma unroll
      for(int mt=0;mt<2;mt++)
        #pragma unroll
        for(int t2=0;t2<8;t2++)
          #pragma unroll
          for(int r=0;r<4;r++)
            A[(mt*16+quad*4+r)*STRIDE + 32 + t2*16 + l15] = f2bf(fp[mt][t2][r]-mean[t2]);
      write_xyz_chunk0(A,lane,xn,yn,zn);   // w_in chunk0
      // GEMM3: w_in(32x160) @ W3 -> relu -> H3
      zero_C(C); load_bias(b3,l15,bb);
      run_gemm<5>(A, wsw+OFF_G3, lane,l15,quad, C);
      store_act(A,l15,quad,C,bb);
      // GEMM4: H3 @ W4 -> sigmoid -> alpha; f_out = sum_k alpha*f_prime
      zero_C(C); load_bias(b4,l15,bb);
      run_gemm<4>(A, wsw+OFF_G4, lane,l15,quad, C);
      float* fo = fout + (size_t)widx*128;
      #pragma unroll
      for(int t2=0;t2<8;t2++){
        float part=0.f;
        #pragma unroll
        for(int mt=0;mt<2;mt++)
          #pragma unroll
          for(int r=0;r<4;r++){
            float pre = C[mt][t2][r]+bb[t2];
            float aa = 1.f/(1.f+__expf(-pre));
            part += aa*fp[mt][t2][r];
          }
        part += __shfl_xor(part,16); part += __shfl_xor(part,32);
        if(quad==0) fo[t2*16+l15] = part;
      }
    }
  }
}

// ---------------------------------------------------------------- launch
extern "C" void kernel_launch(void* const* d_in, const int* in_sizes, int n_in,
                              void* d_out, int out_size, void* d_ws, size_t ws_size,
                              hipStream_t stream){
  (void)in_sizes; (void)n_in; (void)out_size; (void)ws_size;
  const float* xyz   = (const float*)d_in[0];
  const float* feats = (const float*)d_in[1];
  const float* W1 = (const float*)d_in[2]; const float* b1 = (const float*)d_in[3];
  const float* W2 = (const float*)d_in[4]; const float* b2 = (const float*)d_in[5];
  const float* W3 = (const float*)d_in[6]; const float* b3 = (const float*)d_in[7];
  const float* W4 = (const float*)d_in[8]; const float* b4 = (const float*)d_in[9];
  float* out = (float*)d_out;
  float* newxyz = out;               // (16,1024,3) f32
  float* fout   = out + 16*1024*3;   // (16,1024,128) f32
  u16* wsw = (u16*)d_ws;             // 128 KiB swizzled bf16 weights — only ws use

  hipLaunchKernelGGL(swz_kernel, dim3(32), dim3(256), 0, stream, W1,W2,W3,W4, wsw);
  void* args[9];
  args[0]=(void*)&xyz;  args[1]=(void*)&feats; args[2]=(void*)&wsw;
  args[3]=(void*)&b1;   args[4]=(void*)&b2;    args[5]=(void*)&b3; args[6]=(void*)&b4;
  args[7]=(void*)&newxyz; args[8]=(void*)&fout;
  hipLaunchCooperativeKernel((void*)fused_kernel, dim3(NBLK), dim3(512), args, 0, stream);
}

// Round 12
// 826.383 us; speedup vs baseline: 1.0816x; 1.0039x over previous
//
#include <hip/hip_runtime.h>

typedef unsigned short u16;
typedef unsigned int   u32;
typedef unsigned long long u64;
typedef short s8v __attribute__((ext_vector_type(8)));   // 8 bf16 (4 VGPRs)
typedef float f4v __attribute__((ext_vector_type(4)));   // 4 fp32 acc
typedef float f2v __attribute__((ext_vector_type(2)));   // packed fp32 pair
typedef unsigned long long ull2 __attribute__((ext_vector_type(2)));

#define STRIDE 168           // LDS A-row stride in elems (336B, 16B-aligned rows)
#define CAP 256              // ball-query cap (Poisson lambda~137, P(>256)~1e-24)
#define OFF_G1 0             // swizzled-weight elem offsets in ws (128 KiB total)
#define OFF_G2 12288
#define OFF_G3 28672
#define OFF_G4 49152
#define NBLK 240             // cooperative grid — REQUIRED. Regular launch of this
                             // persistent pattern hard-failed twice (R10/R11);
                             // cooperative guarantees co-residency AND replays
                             // safely (roles are blockIdx-derived).
#define PAIR_TASKS 2048      // 2 batches x 1024 samples per XCD-pair
#define WREG 12944           // consumer bytes/wave: Bc 2064 + sel 128 + A 10752
#define HDR 160              // LDS header: fps_done + red2[2][4] (never aliased)

// flags in module memory; one 64B line per counter. Re-zeroed by swz_kernel.
__device__ u32 g_prog[16*16];     // per-batch fps progress
__device__ u32 g_ticket[8*16];    // per-pair task tickets (pair p = batches 2p,2p+1)

__device__ __forceinline__ u16 f2bf(float f){
  u32 u = __float_as_uint(f);
  return (u16)((u + 0x7FFFu + ((u>>16)&1u)) >> 16);      // RNE
}
// exact fp32, no-FMA, numpy order: (dx*dx + dy*dy) + dz*dz
__device__ __forceinline__ float sqd(float ax,float ay,float az,float bx,float by,float bz){
  float dx=ax-bx, dy=ay-by, dz=az-bz;
  return __fadd_rn(__fadd_rn(__fmul_rn(dx,dx),__fmul_rn(dy,dy)),__fmul_rn(dz,dz));
}

// DPP u32 max step (dist bits are positive floats -> unsigned == float ordering)
#define WMAX_STEP(v, CTRL) { \
  u32 _t = (u32)__builtin_amdgcn_update_dpp(0, (int)(v), CTRL, 0xf, 0xf, false); \
  (v) = (v) > _t ? (v) : _t; }
// u64 max step via DPP (all lanes valid with quad_perm patterns)
#define QMAX64(k, CTRL) { \
  u32 _lo=(u32)(k), _hi=(u32)((k)>>32); \
  u32 _plo=(u32)__builtin_amdgcn_update_dpp(0,(int)_lo,CTRL,0xf,0xf,true); \
  u32 _phi=(u32)__builtin_amdgcn_update_dpp(0,(int)_hi,CTRL,0xf,0xf,true); \
  u64 _o=((u64)_phi<<32)|_plo; (k) = (k)>_o ? (k) : _o; }

// relaxed agent-scope store/load (coherence-point path; proven cross-XCD
// coherent by R3-R9 passing runs)
__device__ __forceinline__ void st_rlx(u32* p, u32 v){
  __hip_atomic_store(p, v, __ATOMIC_RELAXED, __HIP_MEMORY_SCOPE_AGENT);
}
__device__ __forceinline__ u32 ld_rlx(const u32* p){
  return __hip_atomic_load(p, __ATOMIC_RELAXED, __HIP_MEMORY_SCOPE_AGENT);
}
// LDS relaxed ops (plain ds_read/ds_write; atomics prevent compiler reg-caching)
__device__ __forceinline__ void st_lds64(u64* p, u64 v){
  __hip_atomic_store(p, v, __ATOMIC_RELAXED, __HIP_MEMORY_SCOPE_WORKGROUP);
}
__device__ __forceinline__ u64 ld_lds64(const u64* p){
  return __hip_atomic_load(p, __ATOMIC_RELAXED, __HIP_MEMORY_SCOPE_WORKGROUP);
}

// ---------------------------------------------------------------- weight swizzle (f32 -> bf16 frags)
__global__ __launch_bounds__(256) void swz_kernel(const float* __restrict__ W1,const float* __restrict__ W2,
                                                  const float* __restrict__ W3,const float* __restrict__ W4,
                                                  u16* __restrict__ wsw){
  int T = blockIdx.x*256 + threadIdx.x;       // 8192 threads
  const float* W; int rel, base, kind;
  if(T < 1536){ rel=T;      base=OFF_G1; W=W1; kind=0; }
  else if(T < 3584){ rel=T-1536; base=OFF_G2; W=W2; kind=1; }
  else if(T < 6144){ rel=T-3584; base=OFF_G3; W=W3; kind=0; }
  else         { rel=T-6144; base=OFF_G4; W=W4; kind=1; }
  int chunk=rel>>6, lane=rel&63, c=chunk>>3, t=chunk&7, quad=lane>>4, l15=lane&15;
  u16 v[8];
  #pragma unroll
  for(int j=0;j<8;j++){
    int kp = c*32 + quad*8 + j, n = t*16 + l15;
    int src = (kind==0) ? (kp<3 ? kp : (kp>=32 ? kp-29 : -1)) : kp;
    v[j] = (src<0) ? (u16)0 : f2bf(W[src*128 + n]);
  }
  int4 o;
  o.x=(int)((u32)v[0]|((u32)v[1]<<16)); o.y=(int)((u32)v[2]|((u32)v[3]<<16));
  o.z=(int)((u32)v[4]|((u32)v[5]<<16)); o.w=(int)((u32)v[6]|((u32)v[7]<<16));
  *(int4*)&wsw[base + rel*8] = o;
  if(T==0){
    #pragma unroll
    for(int i=0;i<256;i++) g_prog[i]=0;
    #pragma unroll
    for(int i=0;i<128;i++) g_ticket[i]=0;
  }
}

// ---------------------------------------------------------------- MLP helpers
__device__ __forceinline__ void zero_C(f4v C[2][8]){
  #pragma unroll
  for(int mt=0;mt<2;mt++)
    #pragma unroll
    for(int t=0;t<8;t++) C[mt][t] = (f4v){0.f,0.f,0.f,0.f};
}
__device__ __forceinline__ void load_bias(const float* bsrc,int l15,float bb[8]){
  #pragma unroll
  for(int t=0;t<8;t++) bb[t]=bsrc[t*16+l15];
}
template<int KC>
__device__ __forceinline__ void run_gemm(const u16* A, const u16* BW,
                                         int lane,int l15,int quad, f4v C[2][8]){
  s8v af[2][KC];
  #pragma unroll
  for(int mt=0;mt<2;mt++)
    #pragma unroll
    for(int c=0;c<KC;c++)
      af[mt][c] = *(const s8v*)&A[(mt*16+l15)*STRIDE + c*32 + quad*8];
  #pragma unroll
  for(int t=0;t<8;t++){
    #pragma unroll
    for(int c=0;c<KC;c++){
      s8v bw = *(const s8v*)&BW[((c*8+t)*64 + lane)*8];
      C[0][t] = __builtin_amdgcn_mfma_f32_16x16x32_bf16(af[0][c],bw,C[0][t],0,0,0);
      C[1][t] = __builtin_amdgcn_mfma_f32_16x16x32_bf16(af[1][c],bw,C[1][t],0,0,0);
    }
  }
}
__device__ __forceinline__ void store_act(u16* A,int l15,int quad,f4v C[2][8],const float bb[8]){
  #pragma unroll
  for(int mt=0;mt<2;mt++)
    #pragma unroll
    for(int t=0;t<8;t++)
      #pragma unroll
      for(int r=0;r<4;r++){
        float v = fmaxf(C[mt][t][r]+bb[t], 0.f);
        A[(mt*16+quad*4+r)*STRIDE + t*16 + l15] = f2bf(v);
      }
}
__device__ __forceinline__ void write_xyz_chunk0(u16* A,int lane,float xn,float yn,float zn){
  if(lane<32){
    u16* row=&A[lane*STRIDE];
    row[0]=f2bf(xn); row[1]=f2bf(yn); row[2]=f2bf(zn); row[3]=0;
    #pragma unroll
    for(int q=0;q<7;q++) *(u64*)&row[4+q*4] = 0ull;   // cols 4..31 zero
  }
}

// ---------------------------------------------------------------- fused producer/consumer kernel
// R12 = R9 restored exactly (last proven pass, 829.6us). Cooperative launch.
// blocks 0..15: 4-wave FPS (1 wave/SIMD, 16 pts/thread); in-loop sync =
//   4-wave LDS flag-sync (tag+parity, quad_perm QMAX64 reduce); waves 4-7
//   idle on fps_done then consume. Centers: per-iter st_rlx by tid==0,
//   vmcnt(3)+prog publish at (i&31)==31, final vmcnt(0)+1024.
// consumers: XCD batch-affinity + work stealing; relaxed polls.
// Structural floor evidence: producer 737±1us across 5 variants (R6-R9) —
// throttle-bound, not code-bound; remaining ~90us is launch overhead that
// only a regular launch would remove (hard-fails in this harness, R10/R11).
__global__ __launch_bounds__(512,2) void fused_kernel(const float* __restrict__ xyz,
    const float* __restrict__ feats, const u16* __restrict__ wsw,
    const float* __restrict__ b1,const float* __restrict__ b2,
    const float* __restrict__ b3,const float* __restrict__ b4,
    float* __restrict__ newxyz, float* __restrict__ fout){
  __shared__ __align__(16) char LB[HDR + 8*WREG];   // 103712 B
  const int tid=threadIdx.x, lane=tid&63, wv=tid>>6;
  u32* fps_done = (u32*)LB;
  u64* red2 = (u64*)(LB + 16);                      // red2[parity*4 + wv], 64B

  if(blockIdx.x < 16){
    const int b = blockIdx.x;
    float* S = (float*)(LB + HDR);                  // 48KB, aliases regions 0-3
    const float* xb = xyz + (size_t)b*4096*3;
    #pragma unroll
    for(int j=0;j<6;j++) ((float4*)S)[j*512+tid] = ((const float4*)xb)[j*512+tid];
    if(tid==0){
      *fps_done = 0;
      #pragma unroll
      for(int q=0;q<8;q++) red2[q] = ~0ull;         // tag 1023: no false match for i=1..1022
    }
    __syncthreads();                                 // once, all 8 waves

    if(wv < 4){
      // ---------------- FPS: 4 waves, 16 pts/thread ----------------
      f2v X[8],Y[8],Z[8],DM[8];
      const float x0=S[0], y0=S[1], z0=S[2];
      {
        #pragma clang fp contract(off)
        const f2v fx2={x0,x0}, fy2={y0,y0}, fz2={z0,z0};
        #pragma unroll
        for(int k2=0;k2<8;k2++){
          int p0 = tid*16 + 2*k2;
          X[k2] = (f2v){S[p0*3],   S[p0*3+3]};
          Y[k2] = (f2v){S[p0*3+1], S[p0*3+4]};
          Z[k2] = (f2v){S[p0*3+2], S[p0*3+5]};
          f2v dx=X[k2]-fx2, dy=Y[k2]-fy2, dz=Z[k2]-fz2;
          DM[k2] = (dx*dx + dy*dy) + dz*dz;
        }
      }
      u32* nbu = (u32*)(newxyz + (size_t)b*3072);
      if(tid==0){
        st_rlx(&nbu[0], __float_as_uint(x0));
        st_rlx(&nbu[1], __float_as_uint(y0));
        st_rlx(&nbu[2], __float_as_uint(z0));
      }
      for(int i=1;i<1024;i++){
        // local max over 16 pts (8 f2v)
        f2v a0 = __builtin_elementwise_max(DM[0],DM[1]);
        f2v a1 = __builtin_elementwise_max(DM[2],DM[3]);
        f2v a2 = __builtin_elementwise_max(DM[4],DM[5]);
        f2v a3 = __builtin_elementwise_max(DM[6],DM[7]);
        f2v b0 = __builtin_elementwise_max(a0,a1);
        f2v b1v= __builtin_elementwise_max(a2,a3);
        f2v mm = __builtin_elementwise_max(b0,b1v);
        float vm = fmaxf(mm[0], mm[1]);
        // first-occurrence local index (bit j <-> pt j, 16 pts)
        u32 m16 = 0;
        #pragma unroll
        for(int j=0;j<16;j++) m16 |= (DM[j>>1][j&1]==vm) ? (1u<<j) : 0u;
        int jm = __ffs(m16)-1;
        // wave max via DPP (6 steps), result lane 63
        u32 w = __float_as_uint(vm);
        WMAX_STEP(w, 0x111); WMAX_STEP(w, 0x112); WMAX_STEP(w, 0x114);
        WMAX_STEP(w, 0x118); WMAX_STEP(w, 0x142); WMAX_STEP(w, 0x143);
        u32 wm = (u32)__builtin_amdgcn_readlane((int)w, 63);
        u64 msk = __ballot(__float_as_uint(vm) == wm);
        int ldr = __ffsll((unsigned long long)msk) - 1;
        int pj  = __builtin_amdgcn_readlane(jm, ldr);
        int p   = (wv*64 + ldr)*16 + pj;               // global idx, <=4095 (12 bits)
        // ---- 4-wave flag-sync reduce (no s_barrier) ----
        const u32 tag = (u32)i & 1023u;
        u64 mykey = ((u64)wm<<32) | ((u64)(((u32)~p)&0xFFFu)<<20) | tag;
        if(lane==0) st_lds64(&red2[(i&1)*4 + wv], mykey);
        __asm__ __volatile__("" ::: "memory");
        u64 k;
        do { k = ld_lds64(&red2[(i&1)*4 + (lane&3)]); }
        while(!__all((u32)(k & 1023ull) == tag));
        QMAX64(k, 0xB1);   // quad_perm [1,0,3,2]
        QMAX64(k, 0x4E);   // quad_perm [2,3,0,1]
        int far = (int)((~(u32)(k>>20)) & 0xFFFu);
        float fx=S[far*3], fy=S[far*3+1], fz=S[far*3+2];
        if(tid==0){
          u32* r = nbu + (size_t)i*3;
          st_rlx(&r[0], __float_as_uint(fx));
          st_rlx(&r[1], __float_as_uint(fy));
          st_rlx(&r[2], __float_as_uint(fz));
          if((i&31)==31){
            __asm__ __volatile__("s_waitcnt vmcnt(3)" ::: "memory");  // older stores retired
            st_rlx(&g_prog[b*16], (u32)i);                            // lag-one publish
          }
        }
        {
          #pragma clang fp contract(off)
          const f2v fx2={fx,fx}, fy2={fy,fy}, fz2={fz,fz};
          #pragma unroll
          for(int k2c=0;k2c<8;k2c++){
            f2v dx=X[k2c]-fx2, dy=Y[k2c]-fy2, dz=Z[k2c]-fz2;
            f2v s2 = (dx*dx + dy*dy) + dz*dz;
            DM[k2c] = __builtin_elementwise_min(DM[k2c], s2);
          }
        }
      }
      // exit sync (round 1024, tag 0, parity 0): all S reads complete before
      // any producer wave starts consuming (regions 0-3 alias S)
      {
        if(lane==0) st_lds64(&red2[0*4 + wv], 0ull);
        __asm__ __volatile__("" ::: "memory");
        u64 k;
        do { k = ld_lds64(&red2[0*4 + (lane&3)]); }
        while(!__all((u32)(k & 1023ull) == 0u));
      }
      if(tid==0){
        __asm__ __volatile__("s_waitcnt vmcnt(0)" ::: "memory");
        st_rlx(&g_prog[b*16], 1024u);
        __hip_atomic_store(fps_done, 1u, __ATOMIC_RELAXED, __HIP_MEMORY_SCOPE_WORKGROUP);
      }
    } else {
      // waves 4-7: idle during FPS (no issue-slot theft), then consume
      while(__hip_atomic_load(fps_done, __ATOMIC_RELAXED, __HIP_MEMORY_SCOPE_WORKGROUP) == 0u)
        __builtin_amdgcn_s_sleep(32);
    }
  }

  // ---------------- persistent consumer (fused ballq + mlp, per-wave) ----------------
  const int quad=lane>>4, l15=lane&15;
  char* wr  = LB + HDR + wv*WREG;
  u64* Bc   = (u64*)wr;
  int* selw = (int*)(wr + 2064);
  u16* A    = (u16*)(wr + 2192);
  const u64 lt = (1ull<<lane)-1ull;
  // physical XCD id -> batch-pair affinity (HW-measured: returns 0..7)
  u32 xcc;
  __asm__ __volatile__("s_getreg_b32 %0, hwreg(HW_REG_XCC_ID)" : "=s"(xcc));
  const int mypair = (int)(xcc & 7u);
  for(int pk=0; pk<8; pk++){                 // own pair first, then steal
    const int pair = (mypair + pk) & 7;
    for(;;){
      int t;
      if(lane==0) t = (int)atomicAdd(&g_ticket[pair*16], 1u);
      t = __shfl(t, 0);
      if(t >= PAIR_TASKS) break;
      const int s = t>>1, tb = pair*2 + (t&1), widx = (tb<<10) + s;
      // relaxed poll: cache-bypassing load, no invalidate
      for(;;){
        u32 pr = ld_rlx(&g_prog[tb*16]);
        if(pr > (u32)s) break;
        __builtin_amdgcn_s_sleep(16);
      }
      __asm__ __volatile__("" ::: "memory");   // keep loads below the poll
      const float* xb = xyz + (size_t)tb*4096*3;
      // centers via relaxed agent loads (same coherence path as producer stores)
      const u32* cpu = (const u32*)(newxyz + (size_t)widx*3);
      const float cx = __uint_as_float(ld_rlx(&cpu[0]));
      const float cy = __uint_as_float(ld_rlx(&cpu[1]));
      const float cz = __uint_as_float(ld_rlx(&cpu[2]));

      // ---- ball query (1 wave) ----
      int base=0;
      for(int kk=0;kk<64;kk++){
        int p = kk*64 + lane;
        float d = sqd(cx,cy,cz, xb[p*3],xb[p*3+1],xb[p*3+2]);
        bool in = (d <= 0.04f);
        u64 m = __ballot(in);
        if(in){ int pos = base + __popcll(m&lt); if(pos<CAP) Bc[pos] = ((u64)__float_as_uint(d)<<32)|(u32)p; }
        base += __popcll(m);
      }
      int cnt = base>CAP ? CAP : base;
      if(cnt > 32){
        if(lane==0){ Bc[cnt]=~0ull; Bc[cnt+1]=~0ull; }     // sentinels (> any key)
        int cnt2 = (cnt+1)&~1;
        for(int c=lane; c<cnt; c+=64){
          u64 key = Bc[c]; int r=0;
          for(int t2=0;t2<cnt2;t2+=2){
            ull2 k2 = *(const ull2*)&Bc[t2];               // b128: 2 keys/read
            r += (k2[0] < key) ? 1 : 0;
            r += (k2[1] < key) ? 1 : 0;
          }
          if(r < 32) selw[r] = (int)(u32)key;              // low 32 = point index
        }
      } else {
        for(int c=lane; c<cnt; c+=64) selw[c] = (int)(u32)Bc[c];
        int need = 32 - cnt, bq = 0;
        for(int kk=0; kk<64 && bq<need; kk++){
          int p = kk*64 + lane;
          float d = sqd(cx,cy,cz, xb[p*3],xb[p*3+1],xb[p*3+2]);
          bool o = !(d <= 0.04f);
          u64 m = __ballot(o);
          if(o){ int pos = bq + __popcll(m&lt); if(pos<need) selw[cnt+pos] = p; }
          bq += __popcll(m);
        }
      }

      // ---- MLP (1 wave, barrier-free: same-wave LDS ordered by lgkmcnt) ----
      const int gi_f = selw[lane>>1] & 4095;
      const int gi_x = selw[lane & 31] & 4095;
      {
        int r2=lane>>1, h=lane&1;
        const float* fs = feats + ((size_t)tb*4096 + gi_f)*64 + h*32;
        u16* fd = &A[r2*STRIDE + 32 + h*32];
        #pragma unroll
        for(int j=0;j<8;j++){
          float4 v4 = ((const float4*)fs)[j];
          u64 pk4 = (u64)f2bf(v4.x) | ((u64)f2bf(v4.y)<<16)
                  | ((u64)f2bf(v4.z)<<32) | ((u64)f2bf(v4.w)<<48);
          *(u64*)&fd[j*4] = pk4;
        }
      }
      float xn=0.f,yn=0.f,zn=0.f;
      if(lane<32){
        const float* xp = xb + (size_t)gi_x*3;
        xn = xp[0]-cx; yn = xp[1]-cy; zn = xp[2]-cz;
      }
      write_xyz_chunk0(A,lane,xn,yn,zn);

      f4v C[2][8]; float bb[8];
      // GEMM1: f_in(32x96) @ W1 -> relu -> H1
      zero_C(C); load_bias(b1,l15,bb);
      run_gemm<3>(A, wsw+OFF_G1, lane,l15,quad, C);
      store_act(A,l15,quad,C,bb);
      // GEMM2: H1 @ W2 -> relu -> f_prime
      zero_C(C); load_bias(b2,l15,bb);
      run_gemm<4>(A, wsw+OFF_G2, lane,l15,quad, C);
      float fp[2][8][4]; float mean[8];
      #pragma unroll
      for(int t2=0;t2<8;t2++){
        float sm=0.f;
        #pragma unroll
        for(int mt=0;mt<2;mt++)
          #pragma unroll
          for(int r=0;r<4;r++){
            float v = fmaxf(C[mt][t2][r]+bb[t2], 0.f);
            fp[mt][t2][r]=v; sm+=v;
          }
        sm += __shfl_xor(sm,16); sm += __shfl_xor(sm,32);
        mean[t2] = sm*0.03125f;
      }
      #pragma unroll
      for(int mt=0;mt<2;mt++)
        #pragma unroll
        for(int t2=0;t2<8;t2++)
          #pragma unroll
          for(int r=0;r<4;r++)
            A[(mt*16+quad*4+r)*STRIDE + 32 + t2*16 + l15] = f2bf(fp[mt][t2][r]-mean[t2]);
      write_xyz_chunk0(A,lane,xn,yn,zn);   // w_in chunk0
      // GEMM3: w_in(32x160) @ W3 -> relu -> H3
      zero_C(C); load_bias(b3,l15,bb);
      run_gemm<5>(A, wsw+OFF_G3, lane,l15,quad, C);
      store_act(A,l15,quad,C,bb);
      // GEMM4: H3 @ W4 -> sigmoid -> alpha; f_out = sum_k alpha*f_prime
      zero_C(C); load_bias(b4,l15,bb);
      run_gemm<4>(A, wsw+OFF_G4, lane,l15,quad, C);
      float* fo = fout + (size_t)widx*128;
      #pragma unroll
      for(int t2=0;t2<8;t2++){
        float part=0.f;
        #pragma unroll
        for(int mt=0;mt<2;mt++)
          #pragma unroll
          for(int r=0;r<4;r++){
            float pre = C[mt][t2][r]+bb[t2];
            float aa = 1.f/(1.f+__expf(-pre));
            part += aa*fp[mt][t2][r];
          }
        part += __shfl_xor(part,16); part += __shfl_xor(part,32);
        if(quad==0) fo[t2*16+l15] = part;
      }
    }
  }
}

// ---------------------------------------------------------------- launch
extern "C" void kernel_launch(void* const* d_in, const int* in_sizes, int n_in,
                              void* d_out, int out_size, void* d_ws, size_t ws_size,
                              hipStream_t stream){
  (void)in_sizes; (void)n_in; (void)out_size; (void)ws_size;
  const float* xyz   = (const float*)d_in[0];
  const float* feats = (const float*)d_in[1];
  const float* W1 = (const float*)d_in[2]; const float* b1 = (const float*)d_in[3];
  const float* W2 = (const float*)d_in[4]; const float* b2 = (const float*)d_in[5];
  const float* W3 = (const float*)d_in[6]; const float* b3 = (const float*)d_in[7];
  const float* W4 = (const float*)d_in[8]; const float* b4 = (const float*)d_in[9];
  float* out = (float*)d_out;
  float* newxyz = out;               // (16,1024,3) f32
  float* fout   = out + 16*1024*3;   // (16,1024,128) f32
  u16* wsw = (u16*)d_ws;             // 128 KiB swizzled bf16 weights — only ws use

  hipLaunchKernelGGL(swz_kernel, dim3(32), dim3(256), 0, stream, W1,W2,W3,W4, wsw);
  void* args[9];
  args[0]=(void*)&xyz;  args[1]=(void*)&feats; args[2]=(void*)&wsw;
  args[3]=(void*)&b1;   args[4]=(void*)&b2;    args[5]=(void*)&b3; args[6]=(void*)&b4;
  args[7]=(void*)&newxyz; args[8]=(void*)&fout;
  hipLaunchCooperativeKernel((void*)fused_kernel, dim3(NBLK), dim3(512), args, 0, stream);
}